// Round 8
// baseline (4660.589 us; speedup 1.0000x reference)
//
#include <hip/hip_runtime.h>

typedef unsigned short u16;
typedef unsigned int u32;
typedef __attribute__((ext_vector_type(8))) short short8;
typedef __attribute__((ext_vector_type(4))) float f32x4;
typedef __attribute__((ext_vector_type(4))) int i32x4;

#define GLP(p) ((const __attribute__((address_space(1))) void*)(p))
#define LDSP(p) ((__attribute__((address_space(3))) void*)(p))

__device__ inline u16 f2bf(float f) {
  unsigned u = __float_as_uint(f);
  return (u16)((u + 0x7fffu + ((u >> 16) & 1u)) >> 16);
}
__device__ inline float bf2f(u16 h) {
  return __uint_as_float(((unsigned)h) << 16);
}
__device__ inline float tanh_fast(float x) {
  float e = __expf(2.0f * x);
  return 1.0f - 2.0f / (e + 1.0f);
}

// ---- LLC-direct (coherence point) access: sc0 sc1 bypass L1/L2 --------------
__device__ inline void store_int_sc(int* p, int v) {
  asm volatile("global_store_dword %0, %1, off sc0 sc1" :: "v"(p), "v"(v) : "memory");
}

// Issue all 32 h-tile loads (16 per buffer) LLC-direct + one drain.
// Chunk i (i=0..7) of a buffer = 8 dwords at base + i*2048 + {0,16}; bases
// a0..a3 = p,p+4096,p+8192,p+12288 (13-bit offset limit), same for b0..b3.
__device__ inline void load32_sc(const char* a0, const char* a1, const char* a2,
                                 const char* a3, const char* b0, const char* b1,
                                 const char* b2, const char* b3,
                                 i32x4 (&r)[16], i32x4 (&s)[16]) {
  asm volatile(
      "global_load_dwordx4 %0, %32, off sc0 sc1\n\t"
      "global_load_dwordx4 %1, %32, off offset:16 sc0 sc1\n\t"
      "global_load_dwordx4 %2, %32, off offset:2048 sc0 sc1\n\t"
      "global_load_dwordx4 %3, %32, off offset:2064 sc0 sc1\n\t"
      "global_load_dwordx4 %4, %33, off sc0 sc1\n\t"
      "global_load_dwordx4 %5, %33, off offset:16 sc0 sc1\n\t"
      "global_load_dwordx4 %6, %33, off offset:2048 sc0 sc1\n\t"
      "global_load_dwordx4 %7, %33, off offset:2064 sc0 sc1\n\t"
      "global_load_dwordx4 %8, %34, off sc0 sc1\n\t"
      "global_load_dwordx4 %9, %34, off offset:16 sc0 sc1\n\t"
      "global_load_dwordx4 %10, %34, off offset:2048 sc0 sc1\n\t"
      "global_load_dwordx4 %11, %34, off offset:2064 sc0 sc1\n\t"
      "global_load_dwordx4 %12, %35, off sc0 sc1\n\t"
      "global_load_dwordx4 %13, %35, off offset:16 sc0 sc1\n\t"
      "global_load_dwordx4 %14, %35, off offset:2048 sc0 sc1\n\t"
      "global_load_dwordx4 %15, %35, off offset:2064 sc0 sc1\n\t"
      "global_load_dwordx4 %16, %36, off sc0 sc1\n\t"
      "global_load_dwordx4 %17, %36, off offset:16 sc0 sc1\n\t"
      "global_load_dwordx4 %18, %36, off offset:2048 sc0 sc1\n\t"
      "global_load_dwordx4 %19, %36, off offset:2064 sc0 sc1\n\t"
      "global_load_dwordx4 %20, %37, off sc0 sc1\n\t"
      "global_load_dwordx4 %21, %37, off offset:16 sc0 sc1\n\t"
      "global_load_dwordx4 %22, %37, off offset:2048 sc0 sc1\n\t"
      "global_load_dwordx4 %23, %37, off offset:2064 sc0 sc1\n\t"
      "global_load_dwordx4 %24, %38, off sc0 sc1\n\t"
      "global_load_dwordx4 %25, %38, off offset:16 sc0 sc1\n\t"
      "global_load_dwordx4 %26, %38, off offset:2048 sc0 sc1\n\t"
      "global_load_dwordx4 %27, %38, off offset:2064 sc0 sc1\n\t"
      "global_load_dwordx4 %28, %39, off sc0 sc1\n\t"
      "global_load_dwordx4 %29, %39, off offset:16 sc0 sc1\n\t"
      "global_load_dwordx4 %30, %39, off offset:2048 sc0 sc1\n\t"
      "global_load_dwordx4 %31, %39, off offset:2064 sc0 sc1\n\t"
      "s_waitcnt vmcnt(0)"
      : "=&v"(r[0]), "=&v"(r[1]), "=&v"(r[2]), "=&v"(r[3]),
        "=&v"(r[4]), "=&v"(r[5]), "=&v"(r[6]), "=&v"(r[7]),
        "=&v"(r[8]), "=&v"(r[9]), "=&v"(r[10]), "=&v"(r[11]),
        "=&v"(r[12]), "=&v"(r[13]), "=&v"(r[14]), "=&v"(r[15]),
        "=&v"(s[0]), "=&v"(s[1]), "=&v"(s[2]), "=&v"(s[3]),
        "=&v"(s[4]), "=&v"(s[5]), "=&v"(s[6]), "=&v"(s[7]),
        "=&v"(s[8]), "=&v"(s[9]), "=&v"(s[10]), "=&v"(s[11]),
        "=&v"(s[12]), "=&v"(s[13]), "=&v"(s[14]), "=&v"(s[15])
      : "v"(a0), "v"(a1), "v"(a2), "v"(a3),
        "v"(b0), "v"(b1), "v"(b2), "v"(b3)
      : "memory");
}

// Poll: reload all 32 until every chunk's epoch (high 16 bits) is current.
__device__ inline void poll_load32(const char* p1, const char* p2,
                                   int need1, int need2,
                                   i32x4 (&r)[16], i32x4 (&s)[16]) {
  for (;;) {
    load32_sc(p1, p1 + 4096, p1 + 8192, p1 + 12288,
              p2, p2 + 4096, p2 + 8192, p2 + 12288, r, s);
    int m1 = 0x7fffffff, m2 = 0x7fffffff;
#pragma unroll
    for (int i = 0; i < 16; ++i) {
      int e = (int)((u32)r[i].x >> 16);
      m1 = m1 < e ? m1 : e;
    }
#pragma unroll
    for (int i = 0; i < 16; ++i) {
      int e = (int)((u32)s[i].x >> 16);
      m2 = m2 < e ? m2 : e;
    }
    if (m1 >= need1 && m2 >= need2) break;
  }
}

// Extract bf16 payloads (low 16 of each dword) into MFMA A-fragments.
__device__ inline void unpack8(const i32x4 (&r)[16], short8 (&H)[8]) {
#pragma unroll
  for (int i = 0; i < 8; ++i) {
    i32x4 lo = r[2 * i], hi = r[2 * i + 1];
    i32x4 p;
    p.x = (lo.x & 0xffff) | (lo.y << 16);
    p.y = (lo.z & 0xffff) | (lo.w << 16);
    p.z = (hi.x & 0xffff) | (hi.y << 16);
    p.w = (hi.z & 0xffff) | (hi.w << 16);
    H[i] = *(const short8*)&p;
  }
}

// ---------------- prep: fp32 -> bf16 conversions, zero h buffers -------------
__device__ inline void convseg(const float* __restrict__ s, u16* __restrict__ d,
                               long n4, long t, long S) {
  for (long i = t; i < n4; i += S) {
    float4 v = ((const float4*)s)[i];
    ushort4 o;
    o.x = f2bf(v.x); o.y = f2bf(v.y); o.z = f2bf(v.z); o.w = f2bf(v.w);
    ((ushort4*)d)[i] = o;
  }
}

__global__ __launch_bounds__(256) void prep_kernel(
    const float* __restrict__ x, const float* __restrict__ wih0,
    const float* __restrict__ whh0, const float* __restrict__ wih1,
    const float* __restrict__ whh1,
    u16* __restrict__ xb, u16* __restrict__ wih0b, u16* __restrict__ whh0b,
    u16* __restrict__ wih1b, u16* __restrict__ whh1b,
    u32* __restrict__ hbufs) {
  long t = blockIdx.x * 256L + threadIdx.x;
  long S = (long)gridDim.x * 256L;
  convseg(x,    xb,    16777216 / 4, t, S);
  convseg(wih0, wih0b,   524288 / 4, t, S);
  convseg(whh0, whh0b,  1048576 / 4, t, S);
  convseg(wih1, wih1b,  1048576 / 4, t, S);
  convseg(whh1, whh1b,  1048576 / 4, t, S);
  // zero h1u + h2u (contiguous): 1 MiB = 65536 int4 (epoch 0, value 0)
  int4 zi = make_int4(0, 0, 0, 0);
  for (long i = t; i < 65536; i += S) ((int4*)hbufs)[i] = zi;
}

// ---------------- GEMM: xp0[m][n] = sum_k x[m][k]*Wih0[n][k] + bih0[n]+bhh0[n]
__global__ __launch_bounds__(256, 2) void gemm_xproj(
    const u16* __restrict__ A,   // 32768 x 512
    const u16* __restrict__ Bw,  // 1024 x 512
    const float* __restrict__ bi, const float* __restrict__ bh,
    u16* __restrict__ C) {       // 32768 x 1024
  __shared__ u16 As[128 * 64];
  __shared__ u16 Bs[128 * 64];
  const int tid = threadIdx.x;
  const int lane = tid & 63;
  const int w = tid >> 6;
  const int ln = lane & 15, kg = lane >> 4;
  const int m0 = blockIdx.x * 128;
  const int n0 = blockIdx.y * 128;
  const int mi = (w & 1) * 64, ni = (w >> 1) * 64;

  f32x4 acc[4][4] = {};
  float bias[4];
#pragma unroll
  for (int nj = 0; nj < 4; ++nj) bias[nj] = bi[n0 + ni + nj * 16 + ln] + bh[n0 + ni + nj * 16 + ln];

  const int lrow = lane >> 3;
  const int lcol = (lane & 7) * 8;

  for (int kt = 0; kt < 512; kt += 64) {
#pragma unroll
    for (int i = 0; i < 4; ++i) {
      int row = i * 32 + w * 8;
      const u16* ga = A + (long)(m0 + row + lrow) * 512 + kt + lcol;
      __builtin_amdgcn_global_load_lds(GLP(ga), LDSP(As + row * 64), 16, 0, 0);
      const u16* gb = Bw + (long)(n0 + row + lrow) * 512 + kt + lcol;
      __builtin_amdgcn_global_load_lds(GLP(gb), LDSP(Bs + row * 64), 16, 0, 0);
    }
    __syncthreads();
#pragma unroll
    for (int kc = 0; kc < 64; kc += 32) {
      short8 af[4], bf[4];
#pragma unroll
      for (int i = 0; i < 4; ++i) {
        af[i] = *(const short8*)(As + (mi + i * 16 + ln) * 64 + kc + kg * 8);
        bf[i] = *(const short8*)(Bs + (ni + i * 16 + ln) * 64 + kc + kg * 8);
      }
#pragma unroll
      for (int a = 0; a < 4; ++a)
#pragma unroll
        for (int b = 0; b < 4; ++b)
          acc[a][b] = __builtin_amdgcn_mfma_f32_16x16x32_bf16(af[a], bf[b], acc[a][b], 0, 0, 0);
    }
    __syncthreads();
  }
#pragma unroll
  for (int a = 0; a < 4; ++a)
#pragma unroll
    for (int b = 0; b < 4; ++b)
#pragma unroll
      for (int r = 0; r < 4; ++r) {
        int m = m0 + mi + a * 16 + kg * 4 + r;
        int n = n0 + ni + b * 16 + ln;
        C[(long)m * 1024 + n] = f2bf(acc[a][b][r] + bias[b]);
      }
}

// ---------------- persistent pipelined 2-layer recurrence --------------------
// 256 blocks x 256 threads; block = (q 0..3) x (c 0..63). h bufs are u32
// epoch-tagged: element = (epoch<<16)|bf16, tile-blocked (16x16 = 1 KiB per
// producer tile; each producer store instruction fills one aligned 64B line).
// NO flags, NO drains: producers fire-and-forget; consumers poll the data's
// epoch fields directly. h1[it] tag = it+1; h2[it-1] tag = it (prezero = 0).
__global__ __launch_bounds__(256, 1) void rnn_persist(
    const u16* __restrict__ whh0, const u16* __restrict__ wih1,
    const u16* __restrict__ whh1, const u16* __restrict__ xp0,
    const float* __restrict__ bih1, const float* __restrict__ bhh1,
    u32* __restrict__ h1u, u32* __restrict__ h2u) {
  const int tid = threadIdx.x;
  const int lane = tid & 63;
  const int w = tid >> 6;
  const int ln = lane & 15, kg = lane >> 4;
  const int q = blockIdx.x >> 6;
  const int c = blockIdx.x & 63;
  const int m0 = q * 16;
  const int j0 = c * 16;
  const int kb = w * 256;  // this wave's K-chunk base (K split 4 ways)

  // persistent weight fragments (B-operand layout: n=lane&15 -> row j0+ln)
  short8 WA[8], W1[8], W2[8];
#pragma unroll
  for (int i = 0; i < 8; ++i) {
    int off = (j0 + ln) * 1024 + kb + i * 32 + kg * 8;
    WA[i] = *(const short8*)(whh0 + off);
    W1[i] = *(const short8*)(wih1 + off);
    W2[i] = *(const short8*)(whh1 + off);
  }
  const float bias1 = bih1[j0 + ln] + bhh1[j0 + ln];

  __shared__ float red[2][2][4][256];  // [it parity][layer][wave][lane*4]

  // consumer per-lane byte base within a region (u32 tiled layout)
  const int cbase = q * 65536 + (w * 16 + (kg >> 1)) * 1024 + ln * 64 + (kg & 1) * 32;
  const char* h1b = (const char*)h1u + cbase;
  const char* h2b = (const char*)h2u + cbase;

  i32x4 rr[16], ss[16];
  short8 H1[8], H2[8];
  u16 xpv[4];

  // ---- pre-loop: h1[-1] region 1, h2[-2] region 0 — prezeroed, no poll -----
  if (w == 0) {
#pragma unroll
    for (int r = 0; r < 4; ++r)
      xpv[r] = xp0[((long)(m0 + kg * 4 + r) * 512 + 0) * 1024 + j0 + ln];
  }
  poll_load32(h1b + 262144, h2b, 0, 0, rr, ss);
  unpack8(rr, H1);
  unpack8(ss, H2);

  for (int it = 0; it <= 512; ++it) {
    const int rp = it & 1;
    f32x4 accA = {}, accB = {};
#pragma unroll
    for (int i = 0; i < 8; ++i) accA = __builtin_amdgcn_mfma_f32_16x16x32_bf16(H1[i], WA[i], accA, 0, 0, 0);
#pragma unroll
    for (int i = 0; i < 8; ++i) accB = __builtin_amdgcn_mfma_f32_16x16x32_bf16(H1[i], W1[i], accB, 0, 0, 0);
#pragma unroll
    for (int i = 0; i < 8; ++i) accB = __builtin_amdgcn_mfma_f32_16x16x32_bf16(H2[i], W2[i], accB, 0, 0, 0);
    *(f32x4*)&red[rp][0][w][lane * 4] = accA;
    *(f32x4*)&red[rp][1][w][lane * 4] = accB;
    __syncthreads();  // the ONLY workgroup barrier this iteration

    if (w == 0) {
      if (it < 512) {  // layer0 epilogue -> h1[it], tag it+1, fire-and-forget
        f32x4 s = *(const f32x4*)&red[rp][0][0][lane * 4];
        s += *(const f32x4*)&red[rp][0][1][lane * 4];
        s += *(const f32x4*)&red[rp][0][2][lane * 4];
        s += *(const f32x4*)&red[rp][0][3][lane * 4];
        u32* h1w = h1u + rp * 65536 + q * 16384 + c * 256;
        const int tag1 = (it + 1) << 16;
#pragma unroll
        for (int r = 0; r < 4; ++r) {
          float z = s[r] + bf2f(xpv[r]);  // D layout: row=kg*4+r, col=ln
          store_int_sc((int*)(h1w + (kg * 4 + r) * 16 + ln),
                       tag1 | (int)f2bf(tanh_fast(z)));
        }
      }
    } else if (w == 1) {
      if (it >= 1) {  // layer1 epilogue -> h2[it-1], tag it, fire-and-forget
        f32x4 s = *(const f32x4*)&red[rp][1][0][lane * 4];
        s += *(const f32x4*)&red[rp][1][1][lane * 4];
        s += *(const f32x4*)&red[rp][1][2][lane * 4];
        s += *(const f32x4*)&red[rp][1][3][lane * 4];
        u32* h2w = h2u + ((it + 1) & 1) * 65536 + q * 16384 + c * 256;
        const int tag2 = it << 16;
#pragma unroll
        for (int r = 0; r < 4; ++r) {
          float z = s[r] + bias1;
          store_int_sc((int*)(h2w + (kg * 4 + r) * 16 + ln),
                       tag2 | (int)f2bf(tanh_fast(z)));
        }
      }
    }

    if (it < 512) {
      if (w == 0 && it < 511) {
#pragma unroll
        for (int r = 0; r < 4; ++r)
          xpv[r] = xp0[((long)(m0 + kg * 4 + r) * 512 + (it + 1)) * 1024 + j0 + ln];
      }
      // data-epoch poll: h1[it] (tag it+1) + h2[it-1] (tag it) in one loop
      const char* p1 = h1b + rp * 262144;
      const char* p2 = h2b + ((it + 1) & 1) * 262144;
      poll_load32(p1, p2, it + 1, it, rr, ss);
      unpack8(rr, H1);
      unpack8(ss, H2);
    }
  }
}

// ---------------- FC head: out[b] = sigmoid(h2[511][b,:] . fc_w + fc_b) ------
// h2[511] lives at parity 1 in the u32 tiled layout (bf16 = low 16 bits).
__global__ __launch_bounds__(256) void fc_kernel(const u32* __restrict__ h2,
                                                 const float* __restrict__ fcw,
                                                 const float* __restrict__ fcb,
                                                 float* __restrict__ out) {
  const int lane = threadIdx.x & 63;
  const int w = threadIdx.x >> 6;
  float wreg[16];
#pragma unroll
  for (int i = 0; i < 16; ++i) wreg[i] = fcw[lane * 16 + i];
  for (int b = w; b < 64; b += 4) {
    const int q = b >> 4, mb = b & 15;
    const u32* hp = h2 + 65536 + q * 16384 + lane * 256 + mb * 16;  // parity 1
    float s = 0.f;
#pragma unroll
    for (int i = 0; i < 16; ++i) s += bf2f((u16)(hp[i] & 0xffffu)) * wreg[i];
#pragma unroll
    for (int off = 32; off > 0; off >>= 1) s += __shfl_down(s, off, 64);
    if (lane == 0) out[b] = 1.0f / (1.0f + __expf(-(s + fcb[0])));
  }
}

extern "C" void kernel_launch(void* const* d_in, const int* in_sizes, int n_in,
                              void* d_out, int out_size, void* d_ws, size_t ws_size,
                              hipStream_t stream) {
  const float* x    = (const float*)d_in[0];
  const float* wih0 = (const float*)d_in[1];
  const float* whh0 = (const float*)d_in[2];
  const float* bih0 = (const float*)d_in[3];
  const float* bhh0 = (const float*)d_in[4];
  const float* wih1 = (const float*)d_in[5];
  const float* whh1 = (const float*)d_in[6];
  const float* bih1 = (const float*)d_in[7];
  const float* bhh1 = (const float*)d_in[8];
  const float* fcw  = (const float*)d_in[9];
  const float* fcb  = (const float*)d_in[10];

  char* ws = (char*)d_ws;
  u16* xb    = (u16*)(ws);                  // 33,554,432 B
  u16* wih0b = (u16*)(ws + 33554432);       //  1,048,576 B
  u16* whh0b = (u16*)(ws + 34603008);       //  2,097,152 B
  u16* wih1b = (u16*)(ws + 36700160);       //  2,097,152 B
  u16* whh1b = (u16*)(ws + 38797312);       //  2,097,152 B
  u16* xp0   = (u16*)(ws + 40894464);       // 67,108,864 B
  u32* h1u   = (u32*)(ws + 108003328);      //    524,288 B (2 regions, tiled)
  u32* h2u   = (u32*)(ws + 108527616);      //    524,288 B (2 regions, tiled)

  prep_kernel<<<1024, 256, 0, stream>>>(x, wih0, whh0, wih1, whh1, xb, wih0b,
                                        whh0b, wih1b, whh1b, h1u);
  dim3 gg(256, 8);
  gemm_xproj<<<gg, 256, 0, stream>>>(xb, wih0b, bih0, bhh0, xp0);
  rnn_persist<<<256, 256, 0, stream>>>(whh0b, wih1b, whh1b, xp0, bih1, bhh1,
                                       h1u, h2u);
  fc_kernel<<<1, 256, 0, stream>>>(h2u, fcw, fcb, (float*)d_out);
}